// Round 8
// baseline (69.862 us; speedup 1.0000x reference)
//
#include <hip/hip_runtime.h>
#include <hip/hip_bf16.h>

// ScatterHorizontal round 8: ZERO-LDS, ZERO-BARRIER streaming MFMA.
// Operand swap: D = W · X^T  (A = W-fragment from prep'd wfrag, B = X-fragment
// gathered DIRECTLY from global: lane = pixel, k = channel -> 8 stride-81 dwords
// per kt). Pixel axis flattened across batches: P = b*81 + p in [0, 82944),
// tiled 5184 x 16 exactly -> no padding, no garbage lanes, no halo.
// Shift d = i-4 handled per-lane: q = p-d, validity cndmask (zero invalid lanes).
// No __syncthreads anywhere -> waves stream independently; full unroll lets the
// compiler software-pipeline loads across offset iterations.
// out[b,o,h,w'] = sum_i [0<=w'-d_i<9]( sum_c W[i,o,c]*x_i[b,c,h,w'-d_i] + bias[i,o] )

#define CIN   64
#define COUT  64
#define NOFF  9
#define HW    81
#define SLAB  5184           // f32 per (b,i) slab

typedef short bf16x8 __attribute__((ext_vector_type(8)));
typedef float f32x4  __attribute__((ext_vector_type(4)));

static __device__ __forceinline__ unsigned int f2bf(float v) {
    union { __hip_bfloat16 h; unsigned short u; } cv;
    cv.h = __float2bfloat16(v);
    return (unsigned int)cv.u;
}

// wfrag flat idx = (((i*2 + kt)*4 + ot)*64 + lane)*8 + j
//   value = bf16( W[i][o = 16*ot + (lane&15)][c = 32*kt + 8*(lane>>4) + j] )
// (serves as the A-fragment now: row m = o_local = lane&15, k = 8*(lane>>4)+j)
__global__ __launch_bounds__(256) void prep_kernel(
    const float* __restrict__ wts,   // [9][64][64] (i,o,c)
    const float* __restrict__ bias,  // [9][64]
    unsigned short* __restrict__ wfrag,
    float* __restrict__ biasEff)     // [9][64] (w,o)
{
    int tid = blockIdx.x * 256 + threadIdx.x;
    int stride = gridDim.x * 256;
    for (int e = tid; e < NOFF * 4096; e += stride) {
        int j  = e & 7;
        int l  = (e >> 3) & 63;
        int ot = (e >> 9) & 3;
        int kt = (e >> 11) & 1;
        int i  = e >> 12;
        int o  = ot * 16 + (l & 15);
        int c  = kt * 32 + (l >> 4) * 8 + j;
        wfrag[e] = (unsigned short)f2bf(wts[(i * COUT + o) * CIN + c]);
    }
    if (blockIdx.x == 0) {
        for (int e = threadIdx.x; e < 9 * COUT; e += 256) {
            int w = e / COUT, o = e - w * COUT;
            int lo = (w - 4 > 0) ? (w - 4) : 0;
            int hi = (w + 4 < 8) ? (w + 4) : 8;
            float s = 0.f;
            for (int i2 = lo; i2 <= hi; ++i2) s += bias[i2 * COUT + o];
            biasEff[e] = s;
        }
    }
}

__global__ __launch_bounds__(256, 4) void scatter_stream_kernel(
    const float* __restrict__ x0, const float* __restrict__ x1,
    const float* __restrict__ x2, const float* __restrict__ x3,
    const float* __restrict__ x4, const float* __restrict__ x5,
    const float* __restrict__ x6, const float* __restrict__ x7,
    const float* __restrict__ x8,
    const unsigned short* __restrict__ wfrag,
    const float* __restrict__ biasEff,
    float* __restrict__ out)
{
    const int t    = threadIdx.x;
    const int wave = t >> 6;
    const int lane = t & 63;
    const int l15  = lane & 15;
    const int lhi  = lane >> 4;          // k-chunk for B, row-quad for C/D

    // this wave's 16-pixel column tile (flattened across batches; exact tiling)
    const int tile = blockIdx.x * 4 + wave;      // 0..5183
    const int P    = tile * 16 + l15;            // lane's pixel id, < 82944
    const int b    = P / 81;
    const int p    = P - b * 81;                 // pixel within batch (h*9+w)
    const int wcol = p % 9;                      // board file w'

    const float* xp[NOFF] = { x0, x1, x2, x3, x4, x5, x6, x7, x8 };

    // accumulators: acc[ot][jj] = D[o = 16ot + 4lhi + jj][col = P] ; init bias
    f32x4 acc[4];
#pragma unroll
    for (int ot = 0; ot < 4; ++ot)
#pragma unroll
        for (int jj = 0; jj < 4; ++jj)
            acc[ot][jj] = biasEff[wcol * COUT + ot * 16 + 4 * lhi + jj];

    // per-lane invariant dword offset: channels 8*lhi + j live at +j*81
    const size_t boff = (size_t)b * SLAB + (size_t)(8 * lhi) * HW;

#pragma unroll
    for (int i = 0; i < NOFF; ++i) {
        const int d     = i - 4;
        const bool valid = (unsigned)(wcol - d) < 9u;
        const int q     = valid ? (p - d) : p;   // invalid lanes: safe in-bounds addr

        // B-fragment: 16 stride-81 dwords (8 per kt), cvt to bf16, mask invalid
        const float* base = xp[i] + boff + q;
        bf16x8 xb[2];
#pragma unroll
        for (int kt = 0; kt < 2; ++kt) {
            const float* sp = base + kt * 2592;  // +32 channels
            float f[8];
#pragma unroll
            for (int j = 0; j < 8; ++j) f[j] = sp[j * HW];
            int4 ai;
            ai.x = f2bf(f[0]) | (f2bf(f[1]) << 16);
            ai.y = f2bf(f[2]) | (f2bf(f[3]) << 16);
            ai.z = f2bf(f[4]) | (f2bf(f[5]) << 16);
            ai.w = f2bf(f[6]) | (f2bf(f[7]) << 16);
            if (!valid) { ai.x = 0; ai.y = 0; ai.z = 0; ai.w = 0; }
            xb[kt] = __builtin_bit_cast(bf16x8, ai);
        }

        // A-fragments (W, L1-hot: same 8 KB slice for every wave on the CU)
#pragma unroll
        for (int kt = 0; kt < 2; ++kt) {
#pragma unroll
            for (int ot = 0; ot < 4; ++ot) {
                bf16x8 aw = *(const bf16x8*)&wfrag[(((i * 2 + kt) * 4 + ot) * 64 + lane) * 8];
                acc[ot] = __builtin_amdgcn_mfma_f32_16x16x32_bf16(aw, xb[kt], acc[ot], 0, 0, 0);
            }
        }
    }

    // store: lane writes its pixel's column: out[b][o][p], o = 16ot + 4lhi + jj
    float* ob = out + ((size_t)b * COUT) * HW + p;
#pragma unroll
    for (int ot = 0; ot < 4; ++ot)
#pragma unroll
        for (int jj = 0; jj < 4; ++jj)
            ob[(ot * 16 + 4 * lhi + jj) * HW] = acc[ot][jj];
}

extern "C" void kernel_launch(void* const* d_in, const int* in_sizes, int n_in,
                              void* d_out, int out_size, void* d_ws, size_t ws_size,
                              hipStream_t stream) {
    const float* x[9];
    for (int i = 0; i < 9; ++i) x[i] = (const float*)d_in[i];
    const float* wts  = (const float*)d_in[9];
    const float* bias = (const float*)d_in[10];
    float* out = (float*)d_out;

    unsigned short* wfrag = (unsigned short*)d_ws;                    // 73728 B
    float* biasEff = (float*)((char*)d_ws + NOFF * 4096 * sizeof(unsigned short));

    prep_kernel<<<144, 256, 0, stream>>>(wts, bias, wfrag, biasEff);
    // 5184 pixel-tiles of 16, 4 waves per block -> 1296 blocks
    scatter_stream_kernel<<<1296, 256, 0, stream>>>(
        x[0], x[1], x[2], x[3], x[4], x[5], x[6], x[7], x[8],
        wfrag, biasEff, out);
}

// Round 9
// 52.531 us; speedup vs baseline: 1.3299x; 1.3299x over previous
//
#include <hip/hip_runtime.h>
#include <hip/hip_bf16.h>

// ScatterHorizontal round 9: R7 h-split (2 blocks/batch, 2x parallelism) with
// XCD-CO-LOCATED pair mapping. Consecutive blockIdx round-robin across the 8
// XCDs, so R7's pair (b,0),(b,1) landed on different XCDs and every 128-B line
// shared by the two halves was fetched into two L2s (FETCH 1.77x). Remap:
//   xcd = bid&7, s = bid>>3, hh = s&1, b = (s>>1)*8 + xcd
// -> both halves of a batch on the SAME XCD at adjacent per-XCD slots; each
// line fetched once. Otherwise byte-identical to R7 (isolates the variable).
// out[b,o,h,w'] = sum_i [0<=w'-d_i<9]( sum_c W[i,o,c]*x_i[b,c,h,w'-d_i] + bias[i,o] )

#define CIN   64
#define COUT  64
#define NOFF  9
#define HW    81
#define SLAB  5184           // f32 per (b,i) slab
#define RSTB  136            // LDS row stride bytes (64 bf16 = 128 + 8 pad)
#define NROW  46             // rows 0..44 data (max), row 45 = zero row
#define ZR    45
#define BUFB  (NROW * RSTB)  // 6256 B per buffer

typedef short bf16x8 __attribute__((ext_vector_type(8)));
typedef float f32x4  __attribute__((ext_vector_type(4)));

static __device__ __forceinline__ unsigned int f2bf(float v) {
    union { __hip_bfloat16 h; unsigned short u; } cv;
    cv.h = __float2bfloat16(v);
    return (unsigned int)cv.u;
}

// wfrag flat idx = (((i*2 + kt)*4 + ot)*64 + lane)*8 + j
//   value = bf16( W[i][o = 16*ot + (lane&15)][c = 32*kt + 8*(lane>>4) + j] )
__global__ __launch_bounds__(256) void prep_kernel(
    const float* __restrict__ wts,   // [9][64][64] (i,o,c)
    const float* __restrict__ bias,  // [9][64]
    unsigned short* __restrict__ wfrag,
    float* __restrict__ biasEff)     // [9][64] (w,o)
{
    int tid = blockIdx.x * 256 + threadIdx.x;
    int stride = gridDim.x * 256;
    for (int e = tid; e < NOFF * 4096; e += stride) {
        int j  = e & 7;
        int l  = (e >> 3) & 63;
        int ot = (e >> 9) & 3;
        int kt = (e >> 11) & 1;
        int i  = e >> 12;
        int o  = ot * 16 + (l & 15);
        int c  = kt * 32 + (l >> 4) * 8 + j;
        wfrag[e] = (unsigned short)f2bf(wts[(i * COUT + o) * CIN + c]);
    }
    if (blockIdx.x == 0) {
        for (int e = threadIdx.x; e < 9 * COUT; e += 256) {
            int w = e / COUT, o = e - w * COUT;
            int lo = (w - 4 > 0) ? (w - 4) : 0;
            int hi = (w + 4 < 8) ? (w + 4) : 8;
            float s = 0.f;
            for (int i2 = lo; i2 <= hi; ++i2) s += bias[i2 * COUT + o];
            biasEff[e] = s;
        }
    }
}

__global__ __launch_bounds__(256, 6) void scatter_mfma7_kernel(
    const float* __restrict__ x0, const float* __restrict__ x1,
    const float* __restrict__ x2, const float* __restrict__ x3,
    const float* __restrict__ x4, const float* __restrict__ x5,
    const float* __restrict__ x6, const float* __restrict__ x7,
    const float* __restrict__ x8,
    const unsigned short* __restrict__ wfrag,
    const float* __restrict__ biasEff,
    float* __restrict__ out)
{
    __shared__ __align__(16) unsigned char xs[2 * BUFB];   // 12512 B

    // XCD-co-located pair mapping (blockIdx % 8 == XCD heuristic, m157/m192):
    // pair (b,0),(b,1) -> same value mod 8 -> same XCD, adjacent slots.
    const int bid  = blockIdx.x;          // 0..2047
    const int xcd  = bid & 7;
    const int s    = bid >> 3;            // per-XCD slot, 0..255
    const int hh   = s & 1;
    const int b    = (s >> 1) * 8 + xcd;  // 0..1023, bijective
    const int npx  = hh ? 36 : 45;        // pixels this block owns
    const int h0w  = hh ? 45 : 0;         // global pixel offset (= h0 * 9)
    const int t    = threadIdx.x;
    const int wid  = t >> 6;              // wave = o-tile (0..3)
    const int lane = t & 63;
    const int l15  = lane & 15;
    const int lhi  = lane >> 4;           // 0..3
    const int ocol = wid * 16 + l15;

    const float* xp[NOFF] = { x0, x1, x2, x3, x4, x5, x6, x7, x8 };

    // ---- staging map (i-invariant): chunk e = q*npx + px, e = t + 256k ----
    int goffk[3], wbytek[3];
    bool actk[3];
    {
        const int nchunk = npx * 16;   // 720 or 576
#pragma unroll
        for (int k = 0; k < 3; ++k) {
            int e = t + 256 * k;
            actk[k] = (e < nchunk);
            int ec = actk[k] ? e : 0;
            int q  = ec / npx;          // runtime div, once per kernel
            int px = ec - q * npx;
            goffk[k]  = q * 324 + px;   // dword offset within (slab + h0w)
            wbytek[k] = px * RSTB + q * 8;
        }
    }

    // A-row constants (i-invariant): m row = pp = mt*16 + l15
    int pAv[3], wAv[3];
#pragma unroll
    for (int mt = 0; mt < 3; ++mt) {
        pAv[mt] = mt * 16 + l15;
        wAv[mt] = (h0w + pAv[mt]) % 9;   // == pAv % 9 since h0w % 9 == 0
    }

    // accumulators init = biasEff[w'][o]
    f32x4 acc[3];
#pragma unroll
    for (int mt = 0; mt < 3; ++mt) {
#pragma unroll
        for (int jj = 0; jj < 4; ++jj) {
            int pp = mt * 16 + lhi * 4 + jj;   // pp <= 47; garbage rows unstored
            acc[mt][jj] = biasEff[(pp % 9) * COUT + ocol];
        }
    }

    // zero row ZR of both buffers (68 dwords)
    if (t < 68) {
        int idx = (t < 34) ? (ZR * RSTB + 4 * t)
                           : (BUFB + ZR * RSTB + 4 * (t - 34));
        *(unsigned int*)&xs[idx] = 0u;
    }

    // ---- prologue: stage slab 0 -> buf 0 ----
    {
        const float* src = xp[0] + (size_t)b * SLAB + h0w;
#pragma unroll
        for (int k = 0; k < 3; ++k) {
            if (actk[k]) {
                const float* sp = src + goffk[k];
                float c0 = sp[0], c1 = sp[81], c2 = sp[162], c3 = sp[243];
                uint2 v;
                v.x = f2bf(c0) | (f2bf(c1) << 16);
                v.y = f2bf(c2) | (f2bf(c3) << 16);
                *(uint2*)&xs[wbytek[k]] = v;
            }
        }
    }
    asm volatile("s_waitcnt lgkmcnt(0)" ::: "memory");
    __builtin_amdgcn_s_barrier();
    __builtin_amdgcn_sched_barrier(0);

#pragma unroll
    for (int i = 0; i < NOFF; ++i) {
        const unsigned char* bufR = &xs[(i & 1) * BUFB];

        // 1) B fragments for this offset (vector loads; wfrag L2-hot)
        bf16x8 bw[2];
#pragma unroll
        for (int kt = 0; kt < 2; ++kt)
            bw[kt] = *(const bf16x8*)&wfrag[(((i * 2 + kt) * 4 + wid) * 64 + lane) * 8];

        // 2) issue stage loads for slab i+1 (latency hides under DS+MFMA phase)
        float sf[3][4];
        if (i + 1 < NOFF) {
            const float* src = xp[i + 1] + (size_t)b * SLAB + h0w;
#pragma unroll
            for (int k = 0; k < 3; ++k) {
                if (actk[k]) {
                    const float* sp = src + goffk[k];
                    sf[k][0] = sp[0];   sf[k][1] = sp[81];
                    sf[k][2] = sp[162]; sf[k][3] = sp[243];
                }
            }
        }

        // 3) A-frag reads (12 x ds_read_b64) + 6 MFMA
        const int d = i - 4;
#pragma unroll
        for (int mt = 0; mt < 3; ++mt) {
            const bool valid = (unsigned)(wAv[mt] - d) < 9u;
            int q = valid ? (pAv[mt] - d) : ZR;   // valid lanes: q in [0,npx)
            if (q > ZR) q = ZR;                   // garbage rows: clamp in-bounds
            const unsigned char* rp = bufR + q * RSTB + lhi * 16;

#pragma unroll
            for (int kt = 0; kt < 2; ++kt) {
                int2 lo = *(const int2*)(rp + kt * 64);
                int2 hi = *(const int2*)(rp + kt * 64 + 8);
                int4 ai = { lo.x, lo.y, hi.x, hi.y };
                bf16x8 af = __builtin_bit_cast(bf16x8, ai);
                acc[mt] = __builtin_amdgcn_mfma_f32_16x16x32_bf16(af, bw[kt], acc[mt], 0, 0, 0);
            }
        }

        // 4) cvt + ds_write slab i+1 into the other buffer; 5) barrier
        if (i + 1 < NOFF) {
            unsigned char* bufW = &xs[((i + 1) & 1) * BUFB];
#pragma unroll
            for (int k = 0; k < 3; ++k) {
                if (actk[k]) {
                    uint2 v;
                    v.x = f2bf(sf[k][0]) | (f2bf(sf[k][1]) << 16);
                    v.y = f2bf(sf[k][2]) | (f2bf(sf[k][3]) << 16);
                    *(uint2*)(bufW + wbytek[k]) = v;
                }
            }
            asm volatile("s_waitcnt lgkmcnt(0)" ::: "memory");
            __builtin_amdgcn_s_barrier();
            __builtin_amdgcn_sched_barrier(0);
        }
    }

    // store: out[b, ocol, p' = h0w + pp] for pp < npx
    float* ob = out + (size_t)b * COUT * HW + (size_t)ocol * HW + h0w;
#pragma unroll
    for (int mt = 0; mt < 3; ++mt) {
#pragma unroll
        for (int jj = 0; jj < 4; ++jj) {
            const int pp = mt * 16 + lhi * 4 + jj;
            if (pp < npx) ob[pp] = acc[mt][jj];
        }
    }
}

extern "C" void kernel_launch(void* const* d_in, const int* in_sizes, int n_in,
                              void* d_out, int out_size, void* d_ws, size_t ws_size,
                              hipStream_t stream) {
    const float* x[9];
    for (int i = 0; i < 9; ++i) x[i] = (const float*)d_in[i];
    const float* wts  = (const float*)d_in[9];
    const float* bias = (const float*)d_in[10];
    float* out = (float*)d_out;

    unsigned short* wfrag = (unsigned short*)d_ws;                    // 73728 B
    float* biasEff = (float*)((char*)d_ws + NOFF * 4096 * sizeof(unsigned short));

    prep_kernel<<<144, 256, 0, stream>>>(wts, bias, wfrag, biasEff);
    scatter_mfma7_kernel<<<2048, 256, 0, stream>>>(
        x[0], x[1], x[2], x[3], x[4], x[5], x[6], x[7], x[8],
        wfrag, biasEff, out);
}